// Round 18
// baseline (307.475 us; speedup 1.0000x reference)
//
#include <hip/hip_runtime.h>
#include <hip/hip_bf16.h>

#define BN_EPS 1e-5f
#define SQ_EPS 1e-8f

typedef __hip_bfloat16 bf16;
typedef __attribute__((ext_vector_type(8))) short bf16x8;
typedef __attribute__((ext_vector_type(4))) float f32x4;

// async global->LDS, 16B per lane; LDS dest is wave-uniform base (+lane*16 by HW)
__device__ __forceinline__ void gload_lds16(const void* g, void* l) {
    __builtin_amdgcn_global_load_lds(
        (const __attribute__((address_space(1))) unsigned int*)g,
        (__attribute__((address_space(3))) unsigned int*)l, 16, 0, 0);
}

__device__ __forceinline__ unsigned short f2bfu(float f) {
    bf16 h = __float2bfloat16(f);
    return *(unsigned short*)&h;
}

// ---------------- merged prep: feat->NHWC | wt1F | wt2F | pad ring --------
// blocks 0..6655 feat (pt,ct,b), 6656..6911 wt1F, 6912..7423 wt2F, 7424+ ring
__global__ __launch_bounds__(256) void prep_all(
    const float* __restrict__ feat, const float* __restrict__ w1,
    const float* __restrict__ w2, bf16* __restrict__ featP,
    bf16* __restrict__ wt1F, bf16* __restrict__ wt2F) {
    int tid = threadIdx.x;
    if (blockIdx.x < 6656) {
        int bid = blockIdx.x;
        int pt = bid % 13, ct = (bid / 13) & 7, b = bid / 104;
        int ci0 = ct * 64, px0 = pt * 64;
        __shared__ float t[64][65];
#pragma unroll
        for (int rep = 0; rep < 16; rep++) {
            int ci_l = rep * 4 + (tid >> 6);
            int px = px0 + (tid & 63);
            float v = 0.f;
            if (px < 784) v = feat[(b * 512 + ci0 + ci_l) * 784 + px];
            t[ci_l][tid & 63] = v;
        }
        __syncthreads();
#pragma unroll
        for (int rep = 0; rep < 4; rep++) {
            int px_l = rep * 16 + (tid >> 4);
            int px = px0 + px_l;
            if (px < 784) {
                int h = px / 28, wq = px % 28;
                int ci = (tid & 15) * 4;
                ushort4 o;
                o.x = f2bfu(t[ci + 0][px_l]);
                o.y = f2bfu(t[ci + 1][px_l]);
                o.z = f2bfu(t[ci + 2][px_l]);
                o.w = f2bfu(t[ci + 3][px_l]);
                *(ushort4*)&featP[((b * 30 + h + 1) * 30 + (wq + 1)) * 512 + ci0 + ci] = o;
            }
        }
        return;
    }
    if (blockIdx.x >= 7424) {
        int b = blockIdx.x - 7424;
        uint4 zz = {0u, 0u, 0u, 0u};
        for (int i = tid; i < 116 * 64; i += 256) {
            int rp = i >> 6;
            int ci = (i & 63) * 8;
            int hp, wp;
            if (rp < 30)      { hp = 0;       wp = rp; }
            else if (rp < 60) { hp = 29;      wp = rp - 30; }
            else if (rp < 88) { hp = rp - 59; wp = 0; }
            else              { hp = rp - 87; wp = 29; }
            *(uint4*)&featP[(b * 900 + hp * 30 + wp) * 512 + ci] = zz;
        }
        return;
    }
    __shared__ float tt[10368];
    if (blockIdx.x < 6912) {
        int co = blockIdx.x - 6656;
        const float* src = w1 + co * 4608;
        for (int i = tid; i < 4608; i += 256) tt[i] = src[i];
        __syncthreads();
        int co16 = co >> 4, l15 = co & 15;
        for (int i = tid; i < 576; i += 256) {   // (g, cc, kq)
            int g = i >> 6, cc = (i >> 2) & 15, kq = i & 3;
            short v[8];
#pragma unroll
            for (int j = 0; j < 8; j++) {
                unsigned short u = f2bfu(tt[(cc * 32 + kq * 8 + j) * 9 + g]);
                v[j] = (short)u;
            }
            int fidx = cc * 9 + g;
            bf16x8* dst = (bf16x8*)&wt1F[(fidx * 16 + co16) * 512 + (kq * 16 + l15) * 8];
            bf16x8 pk = {v[0], v[1], v[2], v[3], v[4], v[5], v[6], v[7]};
            *dst = pk;
        }
    } else {
        int bid = blockIdx.x - 6912;
        int half = bid & 1, co = bid >> 1;
        const float* src = w2 + co * 20736 + half * 10368;
        for (int i = tid; i < 10368; i += 256) tt[i] = src[i];
        __syncthreads();
        int co16 = co >> 4, l15 = co & 15;
        for (int i = tid; i < 1296; i += 256) {  // (sh, ccl, kq)
            int sh = i >> 4, ccl = (i >> 2) & 3, kq = i & 3;
            int z = sh / 10; if (z > 7) z = 7;
            int s0 = (81 * z) >> 3;
            int ns = ((81 * (z + 1)) >> 3) - s0;
            int fidx = s0 * 8 + (half * 4 + ccl) * ns + (sh - s0);
            short v[8];
#pragma unroll
            for (int j = 0; j < 8; j++) {
                unsigned short u = f2bfu(tt[(ccl * 32 + kq * 8 + j) * 81 + sh]);
                v[j] = (short)u;
            }
            bf16x8* dst = (bf16x8*)&wt2F[(fidx * 16 + co16) * 512 + (kq * 16 + l15) * 8];
            bf16x8 pk = {v[0], v[1], v[2], v[3], v[4], v[5], v[6], v[7]};
            *dst = pk;
        }
    }
}

// ---------------- conv1: 112x256 tile, 8 waves, wave=112x32 (frozen) ------
__global__ __launch_bounds__(512, 4) void conv1_mfma(
    const bf16* __restrict__ featP, const bf16* __restrict__ wt1F,
    const float* __restrict__ bias, const float* __restrict__ gamma,
    const float* __restrict__ beta, const float* __restrict__ mean,
    const float* __restrict__ var, bf16* __restrict__ x) {
    __shared__ char As4[4 * 7168];
    const int tid = threadIdx.x, lane = tid & 63, w = tid >> 6;
    const int Mt = blockIdx.x;

    const bf16* pA0;
    {
        int r0 = (w << 4) + (lane >> 2);            // 0..111 used (w<7)
        int q = (lane & 3) ^ ((r0 >> 1) & 3);
        int m0 = Mt * 112 + (w < 7 ? r0 : 0);
        int b0 = m0 / 784, rr = m0 % 784, h0 = rr / 28, w0 = rr % 28;
        pA0 = featP + ((b0 * 30 + h0) * 30 + w0) * 512 + q * 8;
    }
    const bf16x8* pB = (const bf16x8*)wt1F + w * 128 + lane;

    int a_off[7];
#pragma unroll
    for (int mi = 0; mi < 7; mi++) {
        int r = mi * 16 + (lane & 15);
        a_off[mi] = r * 64 + (((lane >> 4) ^ ((r >> 1) & 3)) * 16);
    }

    f32x4 acc[7][2];
#pragma unroll
    for (int i = 0; i < 7; i++)
#pragma unroll
        for (int j = 0; j < 2; j++) acc[i][j] = f32x4{0.f, 0.f, 0.f, 0.f};

    bf16x8 Bv0[2], Bv1[2];

#define STG1(bi, offE)                                                     \
    do {                                                                   \
        if (w < 7)                                                         \
            gload_lds16(pA0 + (offE), As4 + (bi) * 7168 + w * 1024);       \
    } while (0)

    STG1(0, 0); STG1(1, 512); STG1(2, 1024);
    { const bf16x8* bp = pB; Bv0[0] = bp[0]; Bv0[1] = bp[64]; }
    asm volatile("s_waitcnt vmcnt(2)" ::: "memory");  // regions 0..2 landed
    __builtin_amdgcn_s_barrier();
    asm volatile("" ::: "memory");

#define C1_STEP(u, BU, BL)                                                 \
    do {                                                                   \
        const int t_ = t + (u);                                            \
        int ttc = t_ + 3; if (ttc > 143) ttc = 143;                        \
        {                                                                  \
            int cc_ = ttc / 9, g_ = ttc - 9 * cc_;                         \
            int ky_ = g_ / 3, kx_ = g_ - 3 * ky_;                          \
            STG1((u + 3) & 3, (ky_ * 30 + kx_) * 512 + cc_ * 32);          \
        }                                                                  \
        {                                                                  \
            int fn = t_ + 1; if (fn > 143) fn = 143;                       \
            const bf16x8* bp = pB + fn * 1024;                             \
            BL[0] = bp[0]; BL[1] = bp[64];                                 \
        }                                                                  \
        const char* Ab = As4 + (u) * 7168;                                 \
        bf16x8 af[7];                                                      \
        _Pragma("unroll")                                                  \
        for (int mi = 0; mi < 7; mi++)                                     \
            af[mi] = *(const bf16x8*)(Ab + a_off[mi]);                     \
        _Pragma("unroll")                                                  \
        for (int nj = 0; nj < 2; nj++)                                     \
            _Pragma("unroll")                                              \
            for (int mi = 0; mi < 7; mi++)                                 \
                acc[mi][nj] = __builtin_amdgcn_mfma_f32_16x16x32_bf16(     \
                    af[mi], BU[nj], acc[mi][nj], 0, 0, 0);                 \
        if (t_ < 143) {                                                    \
            asm volatile("s_waitcnt vmcnt(8)" ::: "memory");               \
            __builtin_amdgcn_s_barrier();                                  \
            asm volatile("" ::: "memory");                                 \
        }                                                                  \
    } while (0)

    for (int t = 0; t < 144; t += 4) {
        C1_STEP(0, Bv0, Bv1);
        C1_STEP(1, Bv1, Bv0);
        C1_STEP(2, Bv0, Bv1);
        C1_STEP(3, Bv1, Bv0);
    }

#pragma unroll
    for (int nj = 0; nj < 2; nj++) {
        int co = w * 32 + nj * 16 + (lane & 15);
        float inv = gamma[co] * rsqrtf(var[co] + BN_EPS);
        float sh = beta[co] - mean[co] * inv;
        float bs = bias[co];
#pragma unroll
        for (int mi = 0; mi < 7; mi++) {
            int m0 = Mt * 112 + mi * 16 + ((lane >> 4) << 2);
#pragma unroll
            for (int r = 0; r < 4; r++) {
                float v = (acc[mi][nj][r] + bs) * inv + sh;
                x[(m0 + r) * 256 + co] = __float2bfloat16(fmaxf(v, 0.f));
            }
        }
    }
#undef STG1
#undef C1_STEP
}

// ---------------- conv2 (k9 s2): 1-batch x 112-row tile, 512 blocks -------
__global__ __launch_bounds__(512, 4) void conv2_mfma(
    const bf16* __restrict__ x, const bf16* __restrict__ wt2F,
    bf16* __restrict__ p_parts) {
    __shared__ char As4[4 * 7168];
    const int tid = threadIdx.x, lane = tid & 63, w = tid >> 6;
    const int z = blockIdx.x & 7, Mt = blockIdx.x >> 3;   // Mt = batch
    const int sh0 = (81 * z) >> 3, sh1 = (81 * (z + 1)) >> 3;
    const int nsh = sh1 - sh0;                // 10 or 11
    const int NT = nsh << 3;                  // 80 or 88 (both %4==0)
    const int FB = sh0 << 3;

    const bf16* pA0;
    {
        int r0 = (w << 4) + (lane >> 2);      // 0..111 used (w<7)
        int rr = (w < 7) ? r0 : 0;
        int s = rr < 100 ? rr : 99;           // clamp pad rows
        int q = (lane & 3) ^ ((rr >> 1) & 3);
        int ho = s / 10, wo = s - ho * 10;
        pA0 = x + ((Mt * 28 + 2 * ho) * 28 + 2 * wo) * 256 + q * 8;
    }
    const bf16x8* pB = (const bf16x8*)wt2F + w * 128 + lane;

    int a_off[7];
#pragma unroll
    for (int mi = 0; mi < 7; mi++) {
        int r = mi * 16 + (lane & 15);
        a_off[mi] = r * 64 + (((lane >> 4) ^ ((r >> 1) & 3)) * 16);
    }

    f32x4 acc[7][2];
#pragma unroll
    for (int i = 0; i < 7; i++)
#pragma unroll
        for (int j = 0; j < 2; j++) acc[i][j] = f32x4{0.f, 0.f, 0.f, 0.f};

    bf16x8 Bv0[2], Bv1[2];

#define STG2(bi, offE)                                                     \
    do {                                                                   \
        if (w < 7)                                                         \
            gload_lds16(pA0 + (offE), As4 + (bi) * 7168 + w * 1024);       \
    } while (0)

#define A2OFF(tt)                                                          \
    ({ int ttc_ = (tt) < NT ? (tt) : NT - 1;                               \
       int cc_ = ttc_ / nsh, si_ = ttc_ - cc_ * nsh;                       \
       int sh_ = sh0 + si_;                                                \
       int ky_ = sh_ / 9, kx_ = sh_ - 9 * ky_;                             \
       (ky_ * 28 + kx_) * 256 + cc_ * 32; })

    STG2(0, A2OFF(0)); STG2(1, A2OFF(1)); STG2(2, A2OFF(2));
    { const bf16x8* bp = pB + FB * 1024; Bv0[0] = bp[0]; Bv0[1] = bp[64]; }
    asm volatile("s_waitcnt vmcnt(2)" ::: "memory");  // regions 0..2 landed
    __builtin_amdgcn_s_barrier();
    asm volatile("" ::: "memory");

#define C2_STEP(u, BU, BL)                                                 \
    do {                                                                   \
        const int t_ = t + (u);                                            \
        STG2((u + 3) & 3, A2OFF(t_ + 3));                                  \
        {                                                                  \
            int fn = t_ + 1; if (fn > NT - 1) fn = NT - 1;                 \
            const bf16x8* bp = pB + (FB + fn) * 1024;                      \
            BL[0] = bp[0]; BL[1] = bp[64];                                 \
        }                                                                  \
        const char* Ab = As4 + (u) * 7168;                                 \
        bf16x8 af[7];                                                      \
        _Pragma("unroll")                                                  \
        for (int mi = 0; mi < 7; mi++)                                     \
            af[mi] = *(const bf16x8*)(Ab + a_off[mi]);                     \
        _Pragma("unroll")                                                  \
        for (int nj = 0; nj < 2; nj++)                                     \
            _Pragma("unroll")                                              \
            for (int mi = 0; mi < 7; mi++)                                 \
                acc[mi][nj] = __builtin_amdgcn_mfma_f32_16x16x32_bf16(     \
                    af[mi], BU[nj], acc[mi][nj], 0, 0, 0);                 \
        if (t_ < NT - 1) {                                                 \
            asm volatile("s_waitcnt vmcnt(8)" ::: "memory");               \
            __builtin_amdgcn_s_barrier();                                  \
            asm volatile("" ::: "memory");                                 \
        }                                                                  \
    } while (0)

    for (int t = 0; t < NT; t += 4) {
        C2_STEP(0, Bv0, Bv1);
        C2_STEP(1, Bv1, Bv0);
        C2_STEP(2, Bv0, Bv1);
        C2_STEP(3, Bv1, Bv0);
    }

#pragma unroll
    for (int nj = 0; nj < 2; nj++) {
        int co = w * 32 + nj * 16 + (lane & 15);
#pragma unroll
        for (int mi = 0; mi < 7; mi++) {
            int row0 = mi * 16 + ((lane >> 4) << 2);
#pragma unroll
            for (int r = 0; r < 4; r++) {
                int row = row0 + r;
                if (row < 100)
                    p_parts[(z * 6400 + Mt * 100 + row) * 256 + co] =
                        __float2bfloat16(acc[mi][nj][r]);
            }
        }
    }
#undef STG2
#undef A2OFF
#undef C2_STEP
}

// ------- fused squash + u_hat: grid (100 rT, 8 bT), block 256 = 8r x 32 ---
__global__ __launch_bounds__(256) void squash_uhat(
    const bf16* __restrict__ pp, const float* __restrict__ pb,
    const float* __restrict__ rw, float* __restrict__ lc,
    bf16* __restrict__ uht) {
    int rT = blockIdx.x, bT = blockIdx.y;
    int rl = threadIdx.x >> 5, jo = threadIdx.x & 31;
    int r = rT * 8 + rl;
    float4 wreg[8];
    const float4* wp4 = (const float4*)(rw + (r * 32 + jo) * 32);
#pragma unroll
    for (int k = 0; k < 8; k++) wreg[k] = wp4[k];
    int cap = r / 100, s = r - cap * 100;
    int co = cap * 32 + jo;
    float bsv = pb[co];
    __shared__ float vrow[8][32];
    for (int b = bT * 8; b < bT * 8 + 8; b++) {
        int m = b * 100 + s;
        float val = bsv;
#pragma unroll
        for (int zz = 0; zz < 8; zz++)
            val += __bfloat162float(pp[(zz * 6400 + m) * 256 + co]);
        float n2 = val * val;
#pragma unroll
        for (int msk = 1; msk < 32; msk <<= 1) n2 += __shfl_xor(n2, msk);
        float scale = n2 / ((1.f + n2) * sqrtf(n2 + SQ_EPS));
        float sval = val * scale;
        lc[(b * 800 + r) * 32 + jo] = sval;
        vrow[rl][jo] = sval;          // same-wave producer/consumer
        float acc = 0.f;
#pragma unroll
        for (int k = 0; k < 8; k++) {
            float4 a = *(const float4*)&vrow[rl][k * 4];
            acc = fmaf(a.x, wreg[k].x, acc);
            acc = fmaf(a.y, wreg[k].y, acc);
            acc = fmaf(a.z, wreg[k].z, acc);
            acc = fmaf(a.w, wreg[k].w, acc);
        }
        uht[(b * 32 + jo) * 800 + r] = __float2bfloat16(acc);
    }
}

// ---------------- fused dynamic routing (3 iters, 512 thr) ----------------
__global__ __launch_bounds__(512) void route_all(
    const bf16* __restrict__ uht, float* __restrict__ vout) {
    extern __shared__ float rs[];      // u[800*33] | lg[1600] | red[512] | vs[32]
    float* u = rs;
    float* lg = rs + 26400;
    float* red = lg + 1600;
    float* vs = red + 512;
    int b = blockIdx.x, tid = threadIdx.x;
    for (int i = tid; i < 25600; i += 512) {
        int jo = i / 800, r = i - jo * 800;
        u[r * 33 + jo] = __bfloat162float(uht[(b * 32 + jo) * 800 + r]);
    }
    for (int i = tid; i < 1600; i += 512) lg[i] = 0.f;
    __syncthreads();
    int jo = tid & 31, rg = tid >> 5;   // 16 r-groups
    for (int it = 0; it < 3; it++) {
        float sp = 0.f;
        for (int r = rg; r < 800; r += 16) {
            float l0 = lg[r * 2], l1 = lg[r * 2 + 1];
            float m = fmaxf(l0, l1);
            float e0 = __expf(l0 - m), e1 = __expf(l1 - m);
            float c = ((jo < 16) ? e0 : e1) / (e0 + e1);
            sp += c * u[r * 33 + jo];
        }
        red[rg * 32 + jo] = sp;
        __syncthreads();
        if (tid < 32) {
            float s = 0.f;
#pragma unroll
            for (int k = 0; k < 16; k++) s += red[k * 32 + tid];
            float n2 = s * s;
#pragma unroll
            for (int m = 1; m < 16; m <<= 1) n2 += __shfl_xor(n2, m);
            float scale = n2 / ((1.f + n2) * sqrtf(n2 + SQ_EPS));
            float v = s * scale;
            vs[tid] = v;
            if (it == 2) vout[b * 32 + tid] = v;
        }
        __syncthreads();
        if (it < 2) {
            for (int r = tid; r < 800; r += 512) {
                float d0 = 0.f, d1 = 0.f;
#pragma unroll
                for (int o = 0; o < 16; o++) {
                    d0 += u[r * 33 + o] * vs[o];
                    d1 += u[r * 33 + 16 + o] * vs[16 + o];
                }
                lg[r * 2] += d0;
                lg[r * 2 + 1] += d1;
            }
            __syncthreads();
        }
    }
}

extern "C" void kernel_launch(void* const* d_in, const int* in_sizes, int n_in,
                              void* d_out, int out_size, void* d_ws, size_t ws_size,
                              hipStream_t stream) {
    const float* feat    = (const float*)d_in[0];
    const float* conv1_w = (const float*)d_in[1];
    const float* conv1_b = (const float*)d_in[2];
    const float* bn_g    = (const float*)d_in[3];
    const float* bn_b    = (const float*)d_in[4];
    const float* bn_m    = (const float*)d_in[5];
    const float* bn_v    = (const float*)d_in[6];
    const float* prim_w  = (const float*)d_in[7];
    const float* prim_b  = (const float*)d_in[8];
    const float* route_w = (const float*)d_in[9];
    float* out = (float*)d_out;

    char* wsb = (char*)d_ws;
    bf16*  featP   = (bf16*)(wsb + 0);            // 58,982,400 B (dead after conv1)
    bf16*  p_parts = (bf16*)(wsb + 0);            // 26,214,400 B (z-major)
    bf16*  uht     = (bf16*)(wsb + 26214400);     //  3,276,800 B
    bf16*  x       = (bf16*)(wsb + 58982400);     // 25,690,112 B (NHWC)
    bf16*  wt1F    = (bf16*)(wsb + 84672512);     //  2,359,296 B
    bf16*  wt2F    = (bf16*)(wsb + 87031808);     // 10,616,832 B

    float* lc_out = out;                  // (64,800,32)
    float* v_out  = out + 64 * 800 * 32;  // (64,2,16)

    hipFuncSetAttribute((const void*)route_all,
                        hipFuncAttributeMaxDynamicSharedMemorySize, 114304);

    prep_all<<<7488, 256, 0, stream>>>(feat, conv1_w, prim_w, featP, wt1F, wt2F);

    conv1_mfma<<<448, 512, 0, stream>>>(
        featP, wt1F, conv1_b, bn_g, bn_b, bn_m, bn_v, x);

    conv2_mfma<<<512, 512, 0, stream>>>(x, wt2F, p_parts);

    squash_uhat<<<dim3(100, 8), 256, 0, stream>>>(
        p_parts, prim_b, route_w, lc_out, uht);

    route_all<<<64, 512, 114304, stream>>>(uht, v_out);
}

// Round 19
// 270.018 us; speedup vs baseline: 1.1387x; 1.1387x over previous
//
#include <hip/hip_runtime.h>
#include <hip/hip_bf16.h>

#define BN_EPS 1e-5f
#define SQ_EPS 1e-8f

typedef __hip_bfloat16 bf16;
typedef __attribute__((ext_vector_type(8))) short bf16x8;
typedef __attribute__((ext_vector_type(4))) float f32x4;

// async global->LDS, 16B per lane; LDS dest is wave-uniform base (+lane*16 by HW)
__device__ __forceinline__ void gload_lds16(const void* g, void* l) {
    __builtin_amdgcn_global_load_lds(
        (const __attribute__((address_space(1))) unsigned int*)g,
        (__attribute__((address_space(3))) unsigned int*)l, 16, 0, 0);
}

__device__ __forceinline__ unsigned short f2bfu(float f) {
    bf16 h = __float2bfloat16(f);
    return *(unsigned short*)&h;
}

// ---------------- feat NCHW fp32 -> padded NHWC bf16 (interior) -----------
// (separate kernel: 16.6KB LDS, high occupancy — r18's merged prep allocated
//  58KB for the branch union and collapsed occupancy)
__global__ __launch_bounds__(256) void feat_to_nhwc(
    const float* __restrict__ feat, bf16* __restrict__ featP) {
    int b = blockIdx.z, ct = blockIdx.y, pt = blockIdx.x;
    int ci0 = ct * 64, px0 = pt * 64;
    int tid = threadIdx.x;
    __shared__ float t[64][65];
#pragma unroll
    for (int rep = 0; rep < 16; rep++) {
        int ci_l = rep * 4 + (tid >> 6);
        int px = px0 + (tid & 63);
        float v = 0.f;
        if (px < 784) v = feat[(b * 512 + ci0 + ci_l) * 784 + px];
        t[ci_l][tid & 63] = v;
    }
    __syncthreads();
#pragma unroll
    for (int rep = 0; rep < 4; rep++) {
        int px_l = rep * 16 + (tid >> 4);
        int px = px0 + px_l;
        if (px < 784) {
            int h = px / 28, wq = px % 28;
            int ci = (tid & 15) * 4;
            ushort4 o;
            o.x = f2bfu(t[ci + 0][px_l]);
            o.y = f2bfu(t[ci + 1][px_l]);
            o.z = f2bfu(t[ci + 2][px_l]);
            o.w = f2bfu(t[ci + 3][px_l]);
            *(ushort4*)&featP[((b * 30 + h + 1) * 30 + (wq + 1)) * 512 + ci0 + ci] = o;
        }
    }
}

// ------- combined weight transform + pad-ring zero ------------------------
// blocks 0..255 -> wt1F (frag t = cc*9+g), 256..767 -> wt2F, 768..831 -> ring
__global__ __launch_bounds__(256) void wF_transform(
    const float* __restrict__ w1, const float* __restrict__ w2,
    bf16* __restrict__ wt1F, bf16* __restrict__ wt2F,
    bf16* __restrict__ featP) {
    __shared__ float tt[10368];
    if (blockIdx.x >= 768) {
        int b = blockIdx.x - 768;
        uint4 zz = {0u, 0u, 0u, 0u};
        for (int i = threadIdx.x; i < 116 * 64; i += 256) {
            int rp = i >> 6;
            int ci = (i & 63) * 8;
            int hp, wp;
            if (rp < 30)      { hp = 0;       wp = rp; }
            else if (rp < 60) { hp = 29;      wp = rp - 30; }
            else if (rp < 88) { hp = rp - 59; wp = 0; }
            else              { hp = rp - 87; wp = 29; }
            *(uint4*)&featP[(b * 900 + hp * 30 + wp) * 512 + ci] = zz;
        }
        return;
    }
    if (blockIdx.x < 256) {
        int co = blockIdx.x;
        const float* src = w1 + co * 4608;
        for (int i = threadIdx.x; i < 4608; i += 256) tt[i] = src[i];
        __syncthreads();
        int co16 = co >> 4, l15 = co & 15;
        for (int i = threadIdx.x; i < 576; i += 256) {   // (g, cc, kq)
            int g = i >> 6, cc = (i >> 2) & 15, kq = i & 3;
            short v[8];
#pragma unroll
            for (int j = 0; j < 8; j++) {
                unsigned short u = f2bfu(tt[(cc * 32 + kq * 8 + j) * 9 + g]);
                v[j] = (short)u;
            }
            int fidx = cc * 9 + g;
            bf16x8* dst = (bf16x8*)&wt1F[(fidx * 16 + co16) * 512 + (kq * 16 + l15) * 8];
            bf16x8 pk = {v[0], v[1], v[2], v[3], v[4], v[5], v[6], v[7]};
            *dst = pk;
        }
    } else {
        int bid = blockIdx.x - 256;
        int half = bid & 1, co = bid >> 1;
        const float* src = w2 + co * 20736 + half * 10368;
        for (int i = threadIdx.x; i < 10368; i += 256) tt[i] = src[i];
        __syncthreads();
        int co16 = co >> 4, l15 = co & 15;
        for (int i = threadIdx.x; i < 1296; i += 256) {  // (sh, ccl, kq)
            int sh = i >> 4, ccl = (i >> 2) & 3, kq = i & 3;
            int z = sh / 10; if (z > 7) z = 7;
            int s0 = (81 * z) >> 3;
            int ns = ((81 * (z + 1)) >> 3) - s0;
            int fidx = s0 * 8 + (half * 4 + ccl) * ns + (sh - s0);
            short v[8];
#pragma unroll
            for (int j = 0; j < 8; j++) {
                unsigned short u = f2bfu(tt[(ccl * 32 + kq * 8 + j) * 81 + sh]);
                v[j] = (short)u;
            }
            bf16x8* dst = (bf16x8*)&wt2F[(fidx * 16 + co16) * 512 + (kq * 16 + l15) * 8];
            bf16x8 pk = {v[0], v[1], v[2], v[3], v[4], v[5], v[6], v[7]};
            *dst = pk;
        }
    }
}

// ---------------- conv1: 112x256 tile, 8 waves, wave=112x32 (frozen) ------
__global__ __launch_bounds__(512, 4) void conv1_mfma(
    const bf16* __restrict__ featP, const bf16* __restrict__ wt1F,
    const float* __restrict__ bias, const float* __restrict__ gamma,
    const float* __restrict__ beta, const float* __restrict__ mean,
    const float* __restrict__ var, bf16* __restrict__ x) {
    __shared__ char As4[4 * 7168];
    const int tid = threadIdx.x, lane = tid & 63, w = tid >> 6;
    const int Mt = blockIdx.x;

    const bf16* pA0;
    {
        int r0 = (w << 4) + (lane >> 2);            // 0..111 used (w<7)
        int q = (lane & 3) ^ ((r0 >> 1) & 3);
        int m0 = Mt * 112 + (w < 7 ? r0 : 0);
        int b0 = m0 / 784, rr = m0 % 784, h0 = rr / 28, w0 = rr % 28;
        pA0 = featP + ((b0 * 30 + h0) * 30 + w0) * 512 + q * 8;
    }
    const bf16x8* pB = (const bf16x8*)wt1F + w * 128 + lane;

    int a_off[7];
#pragma unroll
    for (int mi = 0; mi < 7; mi++) {
        int r = mi * 16 + (lane & 15);
        a_off[mi] = r * 64 + (((lane >> 4) ^ ((r >> 1) & 3)) * 16);
    }

    f32x4 acc[7][2];
#pragma unroll
    for (int i = 0; i < 7; i++)
#pragma unroll
        for (int j = 0; j < 2; j++) acc[i][j] = f32x4{0.f, 0.f, 0.f, 0.f};

    bf16x8 Bv0[2], Bv1[2];

#define STG1(bi, offE)                                                     \
    do {                                                                   \
        if (w < 7)                                                         \
            gload_lds16(pA0 + (offE), As4 + (bi) * 7168 + w * 1024);       \
    } while (0)

    STG1(0, 0); STG1(1, 512); STG1(2, 1024);
    { const bf16x8* bp = pB; Bv0[0] = bp[0]; Bv0[1] = bp[64]; }
    asm volatile("s_waitcnt vmcnt(2)" ::: "memory");  // regions 0..2 landed
    __builtin_amdgcn_s_barrier();
    asm volatile("" ::: "memory");

#define C1_STEP(u, BU, BL)                                                 \
    do {                                                                   \
        const int t_ = t + (u);                                            \
        int ttc = t_ + 3; if (ttc > 143) ttc = 143;                        \
        {                                                                  \
            int cc_ = ttc / 9, g_ = ttc - 9 * cc_;                         \
            int ky_ = g_ / 3, kx_ = g_ - 3 * ky_;                          \
            STG1((u + 3) & 3, (ky_ * 30 + kx_) * 512 + cc_ * 32);          \
        }                                                                  \
        {                                                                  \
            int fn = t_ + 1; if (fn > 143) fn = 143;                       \
            const bf16x8* bp = pB + fn * 1024;                             \
            BL[0] = bp[0]; BL[1] = bp[64];                                 \
        }                                                                  \
        const char* Ab = As4 + (u) * 7168;                                 \
        bf16x8 af[7];                                                      \
        _Pragma("unroll")                                                  \
        for (int mi = 0; mi < 7; mi++)                                     \
            af[mi] = *(const bf16x8*)(Ab + a_off[mi]);                     \
        _Pragma("unroll")                                                  \
        for (int nj = 0; nj < 2; nj++)                                     \
            _Pragma("unroll")                                              \
            for (int mi = 0; mi < 7; mi++)                                 \
                acc[mi][nj] = __builtin_amdgcn_mfma_f32_16x16x32_bf16(     \
                    af[mi], BU[nj], acc[mi][nj], 0, 0, 0);                 \
        if (t_ < 143) {                                                    \
            asm volatile("s_waitcnt vmcnt(8)" ::: "memory");               \
            __builtin_amdgcn_s_barrier();                                  \
            asm volatile("" ::: "memory");                                 \
        }                                                                  \
    } while (0)

    for (int t = 0; t < 144; t += 4) {
        C1_STEP(0, Bv0, Bv1);
        C1_STEP(1, Bv1, Bv0);
        C1_STEP(2, Bv0, Bv1);
        C1_STEP(3, Bv1, Bv0);
    }

#pragma unroll
    for (int nj = 0; nj < 2; nj++) {
        int co = w * 32 + nj * 16 + (lane & 15);
        float inv = gamma[co] * rsqrtf(var[co] + BN_EPS);
        float sh = beta[co] - mean[co] * inv;
        float bs = bias[co];
#pragma unroll
        for (int mi = 0; mi < 7; mi++) {
            int m0 = Mt * 112 + mi * 16 + ((lane >> 4) << 2);
#pragma unroll
            for (int r = 0; r < 4; r++) {
                float v = (acc[mi][nj][r] + bs) * inv + sh;
                x[(m0 + r) * 256 + co] = __float2bfloat16(fmaxf(v, 0.f));
            }
        }
    }
#undef STG1
#undef C1_STEP
}

// ---------------- conv2 (k9 s2): 1-batch x 112-row tile, 512 blocks -------
__global__ __launch_bounds__(512, 4) void conv2_mfma(
    const bf16* __restrict__ x, const bf16* __restrict__ wt2F,
    bf16* __restrict__ p_parts) {
    __shared__ char As4[4 * 7168];
    const int tid = threadIdx.x, lane = tid & 63, w = tid >> 6;
    const int z = blockIdx.x & 7, Mt = blockIdx.x >> 3;   // Mt = batch
    const int sh0 = (81 * z) >> 3, sh1 = (81 * (z + 1)) >> 3;
    const int nsh = sh1 - sh0;                // 10 or 11
    const int NT = nsh << 3;                  // 80 or 88 (both %4==0)
    const int FB = sh0 << 3;

    const bf16* pA0;
    {
        int r0 = (w << 4) + (lane >> 2);      // 0..111 used (w<7)
        int rr = (w < 7) ? r0 : 0;
        int s = rr < 100 ? rr : 99;           // clamp pad rows
        int q = (lane & 3) ^ ((rr >> 1) & 3);
        int ho = s / 10, wo = s - ho * 10;
        pA0 = x + ((Mt * 28 + 2 * ho) * 28 + 2 * wo) * 256 + q * 8;
    }
    const bf16x8* pB = (const bf16x8*)wt2F + w * 128 + lane;

    int a_off[7];
#pragma unroll
    for (int mi = 0; mi < 7; mi++) {
        int r = mi * 16 + (lane & 15);
        a_off[mi] = r * 64 + (((lane >> 4) ^ ((r >> 1) & 3)) * 16);
    }

    f32x4 acc[7][2];
#pragma unroll
    for (int i = 0; i < 7; i++)
#pragma unroll
        for (int j = 0; j < 2; j++) acc[i][j] = f32x4{0.f, 0.f, 0.f, 0.f};

    bf16x8 Bv0[2], Bv1[2];

#define STG2(bi, offE)                                                     \
    do {                                                                   \
        if (w < 7)                                                         \
            gload_lds16(pA0 + (offE), As4 + (bi) * 7168 + w * 1024);       \
    } while (0)

#define A2OFF(tt)                                                          \
    ({ int ttc_ = (tt) < NT ? (tt) : NT - 1;                               \
       int cc_ = ttc_ / nsh, si_ = ttc_ - cc_ * nsh;                       \
       int sh_ = sh0 + si_;                                                \
       int ky_ = sh_ / 9, kx_ = sh_ - 9 * ky_;                             \
       (ky_ * 28 + kx_) * 256 + cc_ * 32; })

    STG2(0, A2OFF(0)); STG2(1, A2OFF(1)); STG2(2, A2OFF(2));
    { const bf16x8* bp = pB + FB * 1024; Bv0[0] = bp[0]; Bv0[1] = bp[64]; }
    asm volatile("s_waitcnt vmcnt(2)" ::: "memory");  // regions 0..2 landed
    __builtin_amdgcn_s_barrier();
    asm volatile("" ::: "memory");

#define C2_STEP(u, BU, BL)                                                 \
    do {                                                                   \
        const int t_ = t + (u);                                            \
        STG2((u + 3) & 3, A2OFF(t_ + 3));                                  \
        {                                                                  \
            int fn = t_ + 1; if (fn > NT - 1) fn = NT - 1;                 \
            const bf16x8* bp = pB + (FB + fn) * 1024;                      \
            BL[0] = bp[0]; BL[1] = bp[64];                                 \
        }                                                                  \
        const char* Ab = As4 + (u) * 7168;                                 \
        bf16x8 af[7];                                                      \
        _Pragma("unroll")                                                  \
        for (int mi = 0; mi < 7; mi++)                                     \
            af[mi] = *(const bf16x8*)(Ab + a_off[mi]);                     \
        _Pragma("unroll")                                                  \
        for (int nj = 0; nj < 2; nj++)                                     \
            _Pragma("unroll")                                              \
            for (int mi = 0; mi < 7; mi++)                                 \
                acc[mi][nj] = __builtin_amdgcn_mfma_f32_16x16x32_bf16(     \
                    af[mi], BU[nj], acc[mi][nj], 0, 0, 0);                 \
        if (t_ < NT - 1) {                                                 \
            asm volatile("s_waitcnt vmcnt(8)" ::: "memory");               \
            __builtin_amdgcn_s_barrier();                                  \
            asm volatile("" ::: "memory");                                 \
        }                                                                  \
    } while (0)

    for (int t = 0; t < NT; t += 4) {
        C2_STEP(0, Bv0, Bv1);
        C2_STEP(1, Bv1, Bv0);
        C2_STEP(2, Bv0, Bv1);
        C2_STEP(3, Bv1, Bv0);
    }

#pragma unroll
    for (int nj = 0; nj < 2; nj++) {
        int co = w * 32 + nj * 16 + (lane & 15);
#pragma unroll
        for (int mi = 0; mi < 7; mi++) {
            int row0 = mi * 16 + ((lane >> 4) << 2);
#pragma unroll
            for (int r = 0; r < 4; r++) {
                int row = row0 + r;
                if (row < 100)
                    p_parts[(z * 6400 + Mt * 100 + row) * 256 + co] =
                        __float2bfloat16(acc[mi][nj][r]);
            }
        }
    }
#undef STG2
#undef A2OFF
#undef C2_STEP
}

// ------- fused squash + u_hat: grid (100 rT, 8 bT), block 256 = 8r x 32 ---
__global__ __launch_bounds__(256) void squash_uhat(
    const bf16* __restrict__ pp, const float* __restrict__ pb,
    const float* __restrict__ rw, float* __restrict__ lc,
    bf16* __restrict__ uht) {
    int rT = blockIdx.x, bT = blockIdx.y;
    int rl = threadIdx.x >> 5, jo = threadIdx.x & 31;
    int r = rT * 8 + rl;
    float4 wreg[8];
    const float4* wp4 = (const float4*)(rw + (r * 32 + jo) * 32);
#pragma unroll
    for (int k = 0; k < 8; k++) wreg[k] = wp4[k];
    int cap = r / 100, s = r - cap * 100;
    int co = cap * 32 + jo;
    float bsv = pb[co];
    __shared__ float vrow[8][32];
    for (int b = bT * 8; b < bT * 8 + 8; b++) {
        int m = b * 100 + s;
        float val = bsv;
#pragma unroll
        for (int zz = 0; zz < 8; zz++)
            val += __bfloat162float(pp[(zz * 6400 + m) * 256 + co]);
        float n2 = val * val;
#pragma unroll
        for (int msk = 1; msk < 32; msk <<= 1) n2 += __shfl_xor(n2, msk);
        float scale = n2 / ((1.f + n2) * sqrtf(n2 + SQ_EPS));
        float sval = val * scale;
        lc[(b * 800 + r) * 32 + jo] = sval;
        vrow[rl][jo] = sval;          // same-wave producer/consumer
        float acc = 0.f;
#pragma unroll
        for (int k = 0; k < 8; k++) {
            float4 a = *(const float4*)&vrow[rl][k * 4];
            acc = fmaf(a.x, wreg[k].x, acc);
            acc = fmaf(a.y, wreg[k].y, acc);
            acc = fmaf(a.z, wreg[k].z, acc);
            acc = fmaf(a.w, wreg[k].w, acc);
        }
        uht[(b * 32 + jo) * 800 + r] = __float2bfloat16(acc);
    }
}

// ---------------- fused dynamic routing (3 iters, 512 thr) ----------------
__global__ __launch_bounds__(512) void route_all(
    const bf16* __restrict__ uht, float* __restrict__ vout) {
    extern __shared__ float rs[];      // u[800*33] | lg[1600] | red[512] | vs[32]
    float* u = rs;
    float* lg = rs + 26400;
    float* red = lg + 1600;
    float* vs = red + 512;
    int b = blockIdx.x, tid = threadIdx.x;
    for (int i = tid; i < 25600; i += 512) {
        int jo = i / 800, r = i - jo * 800;
        u[r * 33 + jo] = __bfloat162float(uht[(b * 32 + jo) * 800 + r]);
    }
    for (int i = tid; i < 1600; i += 512) lg[i] = 0.f;
    __syncthreads();
    int jo = tid & 31, rg = tid >> 5;   // 16 r-groups
    for (int it = 0; it < 3; it++) {
        float sp = 0.f;
        for (int r = rg; r < 800; r += 16) {
            float l0 = lg[r * 2], l1 = lg[r * 2 + 1];
            float m = fmaxf(l0, l1);
            float e0 = __expf(l0 - m), e1 = __expf(l1 - m);
            float c = ((jo < 16) ? e0 : e1) / (e0 + e1);
            sp += c * u[r * 33 + jo];
        }
        red[rg * 32 + jo] = sp;
        __syncthreads();
        if (tid < 32) {
            float s = 0.f;
#pragma unroll
            for (int k = 0; k < 16; k++) s += red[k * 32 + tid];
            float n2 = s * s;
#pragma unroll
            for (int m = 1; m < 16; m <<= 1) n2 += __shfl_xor(n2, m);
            float scale = n2 / ((1.f + n2) * sqrtf(n2 + SQ_EPS));
            float v = s * scale;
            vs[tid] = v;
            if (it == 2) vout[b * 32 + tid] = v;
        }
        __syncthreads();
        if (it < 2) {
            for (int r = tid; r < 800; r += 512) {
                float d0 = 0.f, d1 = 0.f;
#pragma unroll
                for (int o = 0; o < 16; o++) {
                    d0 += u[r * 33 + o] * vs[o];
                    d1 += u[r * 33 + 16 + o] * vs[16 + o];
                }
                lg[r * 2] += d0;
                lg[r * 2 + 1] += d1;
            }
            __syncthreads();
        }
    }
}

extern "C" void kernel_launch(void* const* d_in, const int* in_sizes, int n_in,
                              void* d_out, int out_size, void* d_ws, size_t ws_size,
                              hipStream_t stream) {
    const float* feat    = (const float*)d_in[0];
    const float* conv1_w = (const float*)d_in[1];
    const float* conv1_b = (const float*)d_in[2];
    const float* bn_g    = (const float*)d_in[3];
    const float* bn_b    = (const float*)d_in[4];
    const float* bn_m    = (const float*)d_in[5];
    const float* bn_v    = (const float*)d_in[6];
    const float* prim_w  = (const float*)d_in[7];
    const float* prim_b  = (const float*)d_in[8];
    const float* route_w = (const float*)d_in[9];
    float* out = (float*)d_out;

    char* wsb = (char*)d_ws;
    bf16*  featP   = (bf16*)(wsb + 0);            // 58,982,400 B (dead after conv1)
    bf16*  p_parts = (bf16*)(wsb + 0);            // 26,214,400 B (z-major)
    bf16*  uht     = (bf16*)(wsb + 26214400);     //  3,276,800 B
    bf16*  x       = (bf16*)(wsb + 58982400);     // 25,690,112 B (NHWC)
    bf16*  wt1F    = (bf16*)(wsb + 84672512);     //  2,359,296 B
    bf16*  wt2F    = (bf16*)(wsb + 87031808);     // 10,616,832 B

    float* lc_out = out;                  // (64,800,32)
    float* v_out  = out + 64 * 800 * 32;  // (64,2,16)

    hipFuncSetAttribute((const void*)route_all,
                        hipFuncAttributeMaxDynamicSharedMemorySize, 114304);

    feat_to_nhwc<<<dim3(13, 8, 64), 256, 0, stream>>>(feat, featP);
    wF_transform<<<832, 256, 0, stream>>>(conv1_w, prim_w, wt1F, wt2F, featP);

    conv1_mfma<<<448, 512, 0, stream>>>(
        featP, wt1F, conv1_b, bn_g, bn_b, bn_m, bn_v, x);

    conv2_mfma<<<512, 512, 0, stream>>>(x, wt2F, p_parts);

    squash_uhat<<<dim3(100, 8), 256, 0, stream>>>(
        p_parts, prim_b, route_w, lc_out, uht);

    route_all<<<64, 512, 114304, stream>>>(uht, v_out);
}